// Round 1
// baseline (520.624 us; speedup 1.0000x reference)
//
#include <hip/hip_runtime.h>

#define NN 50000
#define EE 500000
#define GG 512

typedef short short8 __attribute__((ext_vector_type(8)));
typedef float f32x4 __attribute__((ext_vector_type(4)));

__device__ __forceinline__ unsigned short f2bf(float f){
  unsigned u = __float_as_uint(f);
  u += 0x7FFFu + ((u >> 16) & 1u);   // round-to-nearest-even
  return (unsigned short)(u >> 16);
}
__device__ __forceinline__ float bf2f(unsigned short h){
  return __uint_as_float(((unsigned)h) << 16);
}

// ---------------------------------------------------------------------------
// Prep: repack w2/b2 into bf16 B-matrices Bt[o][ki], ki = k*IP + i, k=32 row
// is the bias (h'=1) row, pad rows are zero.
// conv1: IP=8  (i<6 real), K'=288  (9  slices of 32)
// conv2: IP=32,            K'=1088 (34 slices of 32; slice 33 = zero pad)
// ---------------------------------------------------------------------------
__launch_bounds__(256)
__global__ void prep_bt_k(const float* __restrict__ w2a, const float* __restrict__ b2a,
                          const float* __restrict__ w2b, const float* __restrict__ b2b,
                          unsigned short* __restrict__ Bt1, unsigned short* __restrict__ Bt2)
{
  int idx = blockIdx.x*256 + threadIdx.x;
  if (idx < 32*288){
    int o = idx / 288, ki = idx % 288;
    int k = ki >> 3, i = ki & 7;
    float v = 0.f;
    if (i < 6){
      if (k < 32)      v = w2a[k*192 + i*32 + o];
      else if (k == 32) v = b2a[i*32 + o];
    }
    Bt1[idx] = f2bf(v);
  } else {
    int j = idx - 32*288;
    if (j < 32*1088){
      int o = j / 1088, ki = j % 1088;
      int k = ki >> 5, i = ki & 31;
      float v = 0.f;
      if (k < 32)      v = w2b[k*1024 + i*32 + o];
      else if (k == 32) v = b2b[i*32 + o];
      Bt2[j] = f2bf(v);
    }
  }
}

// ---------------------------------------------------------------------------
// NNConv edge-message kernel: per block = 64 edges (4 waves x 16 rows).
// msg = z @ B  via mfma_f32_16x16x32_bf16, z row built on the fly as
// h'[e,k] * x'[e,i].  Scatter via atomicAdd into agg[dst].
// A-frag lane l: row = l&15, k-octet = 8*(l>>4)+j.
// B-frag lane l: col = l&15, same k-octet.  D: col=l&15, row=(l>>4)*4+r.
// ---------------------------------------------------------------------------
template<int IN_C, int IP, int LOG_IP, int KP, int NSLICE, int CHUNK, int ADD_CNT>
__launch_bounds__(256)
__global__ void conv_msg_k(const float* __restrict__ x, const int* __restrict__ ei,
                           const float* __restrict__ ea, const float* __restrict__ w1,
                           const float* __restrict__ b1,
                           const unsigned short* __restrict__ Btg,
                           float* __restrict__ agg, float* __restrict__ cnt, int E)
{
  constexpr int BTSTR = CHUNK*32 + 8;            // u16 stride, row 16B-aligned, bank-spread
  constexpr int XSTR  = (IP == 8) ? 24 : 40;     // u16 stride, 16B-aligned rows
  __shared__ unsigned short Bt[32][BTSTR];
  __shared__ float hs[64][38];                   // h' (32 + bias-one + zero pads)
  __shared__ unsigned short xs[64][XSTR];
  __shared__ float eas[64][5];
  __shared__ float w1s[160];
  __shared__ float b1s[32];
  __shared__ int srcs[64], dsts[64];

  int tid = threadIdx.x;
  int e0  = blockIdx.x * 64;

  if (tid < 160) w1s[tid] = w1[tid];
  if (tid >= 192 && tid < 224) b1s[tid-192] = b1[tid-192];
  if (tid >= 64 && tid < 128){
    int t = tid - 64, e = e0 + t;
    srcs[t] = (e < E) ? ei[e] : 0;
    dsts[t] = (e < E) ? ei[EE + e] : 0;
  }
  for (int idx = tid; idx < 320; idx += 256){
    int e = idx / 5, q = idx - e*5;
    eas[e][q] = (e0 + e < E) ? ea[(long)(e0+e)*5 + q] : 0.f;
  }
  __syncthreads();

  // h' = relu(ea @ w1 + b1); h'[32] = 1 (bias row); pads 33..35 = 0
  {
    int e = tid >> 2, kb = (tid & 3) * 8;
    bool valid = (e0 + e) < E;
    #pragma unroll
    for (int j = 0; j < 8; ++j){
      int k = kb + j;
      float a = b1s[k];
      #pragma unroll
      for (int q = 0; q < 5; ++q) a += eas[e][q] * w1s[q*32 + k];
      hs[e][k] = valid ? fmaxf(a, 0.f) : 0.f;
    }
    if ((tid & 3) == 0){
      hs[e][32] = valid ? 1.f : 0.f;
      hs[e][33] = 0.f; hs[e][34] = 0.f; hs[e][35] = 0.f;
    }
  }
  // x' gather (bf16), zero pads
  for (int idx = tid; idx < 64*IP; idx += 256){
    int e = idx >> LOG_IP, i = idx & (IP-1);
    float v = 0.f;
    if ((e0 + e) < E && i < IN_C) v = x[(long)srcs[e]*IN_C + i];
    xs[e][i] = f2bf(v);
  }

  int lane = tid & 63, wave = tid >> 6;
  int ll = lane & 15, g = (lane >> 4) & 3;
  int erow = wave*16 + ll;
  f32x4 acc0 = {0.f,0.f,0.f,0.f}, acc1 = {0.f,0.f,0.f,0.f};
  float xr[8];

  constexpr int NCH = NSLICE / CHUNK;
  for (int c = 0; c < NCH; ++c){
    __syncthreads();                             // also protects hs/xs on c==0
    {
      constexpr int DWROW = CHUNK*16;            // dwords per Bt row chunk
      for (int idx = tid; idx < 32*DWROW; idx += 256){
        int col = idx / DWROW, q = idx - col*DWROW;
        ((unsigned*)&Bt[col][0])[q] =
            ((const unsigned*)Btg)[col*(KP/2) + c*DWROW + q];
      }
    }
    __syncthreads();
    {
      int xoff = (8*g) & (IP-1);
      short8 xv = *(const short8*)&xs[erow][xoff];
      #pragma unroll
      for (int j = 0; j < 8; ++j) xr[j] = bf2f((unsigned short)xv[j]);
    }
    #pragma unroll
    for (int sl = 0; sl < CHUNK; ++sl){
      int s = c*CHUNK + sl;
      float hv = hs[erow][(32*s + 8*g) >> LOG_IP];
      short8 af;
      #pragma unroll
      for (int j = 0; j < 8; ++j) af[j] = (short)f2bf(hv * xr[j]);
      short8 b0  = *(const short8*)&Bt[ll     ][sl*32 + 8*g];
      short8 b1f = *(const short8*)&Bt[ll + 16][sl*32 + 8*g];
      acc0 = __builtin_amdgcn_mfma_f32_16x16x32_bf16(af, b0,  acc0, 0, 0, 0);
      acc1 = __builtin_amdgcn_mfma_f32_16x16x32_bf16(af, b1f, acc1, 0, 0, 0);
    }
  }

  // epilogue: D lane l reg r -> edge (l>>4)*4+r of this wave, col l&15
  #pragma unroll
  for (int r = 0; r < 4; ++r){
    int eloc = wave*16 + 4*g + r;
    if (e0 + eloc < E){
      long d = dsts[eloc];
      atomicAdd(&agg[d*32 + ll],      acc0[r]);
      atomicAdd(&agg[d*32 + 16 + ll], acc1[r]);
    }
  }
  if (ADD_CNT){
    if (tid < 64 && (e0 + tid) < E) atomicAdd(&cnt[dsts[tid]], 1.f);
  }
}

// ---------------------------------------------------------------------------
// h = agg/max(cnt,1) + x@root + bias (in place), and accumulate BN stats.
// ---------------------------------------------------------------------------
template<int IN_C>
__launch_bounds__(256)
__global__ void node_update_k(const float* __restrict__ xin, const float* __restrict__ root,
                              const float* __restrict__ bias, const float* __restrict__ cnt,
                              float* __restrict__ buf, float* __restrict__ stats, int N)
{
  __shared__ float rs[IN_C*32];
  __shared__ float bs[32];
  __shared__ float redS[4][32], redQ[4][32];
  int tid = threadIdx.x;
  for (int i = tid; i < IN_C*32; i += 256) rs[i] = root[i];
  if (tid < 32) bs[tid] = bias[tid];
  __syncthreads();
  int o = tid & 31, slot = tid >> 5;
  float s = 0.f, q = 0.f;
  for (int n = blockIdx.x*8 + slot; n < N; n += gridDim.x*8){
    float c = fmaxf(cnt[n], 1.f);
    float v = buf[(long)n*32 + o] / c + bs[o];
    const float* xrow = &xin[(long)n*IN_C];
    #pragma unroll
    for (int i = 0; i < IN_C; ++i) v += xrow[i] * rs[i*32 + o];
    buf[(long)n*32 + o] = v;
    s += v; q += v*v;
  }
  s += __shfl_xor(s, 32); q += __shfl_xor(q, 32);
  int wv = tid >> 6;
  if ((tid & 63) < 32){ redS[wv][o] = s; redQ[wv][o] = q; }
  __syncthreads();
  if (tid < 32){
    float ts = 0.f, tq = 0.f;
    #pragma unroll
    for (int w = 0; w < 4; ++w){ ts += redS[w][tid]; tq += redQ[w][tid]; }
    atomicAdd(&stats[tid], ts); atomicAdd(&stats[32 + tid], tq);
  }
}

__launch_bounds__(256)
__global__ void bn_relu_k(float* __restrict__ buf, const float* __restrict__ stats,
                          const float* __restrict__ gg, const float* __restrict__ bb,
                          float invN, int total)
{
  int i = blockIdx.x*256 + threadIdx.x;
  if (i < total){
    int o = i & 31;
    float mu  = stats[o] * invN;
    float var = stats[32+o] * invN - mu*mu;
    float v = (buf[i] - mu) * rsqrtf(var + 1e-5f) * gg[o] + bb[o];
    buf[i] = fmaxf(v, 0.f);
  }
}

__launch_bounds__(256)
__global__ void bn_pool_k(const float* __restrict__ buf, const float* __restrict__ stats,
                          const float* __restrict__ gg, const float* __restrict__ bb,
                          const int* __restrict__ batch, float* __restrict__ psum,
                          float* __restrict__ pcnt, float invN, int N)
{
  int tid = threadIdx.x;
  int o = tid & 31;
  int n = blockIdx.x*8 + (tid >> 5);
  if (n < N){
    int gr = batch[n];
    float mu  = stats[o] * invN;
    float var = stats[32+o] * invN - mu*mu;
    float v = fmaxf((buf[(long)n*32+o] - mu) * rsqrtf(var + 1e-5f) * gg[o] + bb[o], 0.f);
    atomicAdd(&psum[gr*32 + o], v);
    if (o == 0) atomicAdd(&pcnt[gr], 1.f);
  }
}

__launch_bounds__(256)
__global__ void final_k(const float* __restrict__ psum, const float* __restrict__ pcnt,
                        const float* __restrict__ gattr, const float* __restrict__ fcw,
                        const float* __restrict__ fcb, float* __restrict__ out, int G)
{
  int g = blockIdx.x*256 + threadIdx.x;
  if (g < G){
    float c = fmaxf(pcnt[g], 1.f);
    float o0 = fcb[0], o1 = fcb[1], o2 = fcb[2];
    #pragma unroll
    for (int j = 0; j < 32; ++j){
      float p = psum[g*32+j] / c;
      o0 += p*fcw[j*3+0]; o1 += p*fcw[j*3+1]; o2 += p*fcw[j*3+2];
    }
    #pragma unroll
    for (int j = 0; j < 4; ++j){
      float a = gattr[g*4+j];
      o0 += a*fcw[(32+j)*3+0]; o1 += a*fcw[(32+j)*3+1]; o2 += a*fcw[(32+j)*3+2];
    }
    out[g*3+0] = o0; out[g*3+1] = o1; out[g*3+2] = o2;
  }
}

// ---------------------------------------------------------------------------
extern "C" void kernel_launch(void* const* d_in, const int* in_sizes, int n_in,
                              void* d_out, int out_size, void* d_ws, size_t ws_size,
                              hipStream_t stream)
{
  const float* x     = (const float*)d_in[0];
  const int*   ei    = (const int*)  d_in[1];
  const float* ea    = (const float*)d_in[2];
  const int*   batch = (const int*)  d_in[3];
  const float* gattr = (const float*)d_in[4];
  const float* e1_w1 = (const float*)d_in[5];
  const float* e1_b1 = (const float*)d_in[6];
  const float* e1_w2 = (const float*)d_in[7];
  const float* e1_b2 = (const float*)d_in[8];
  const float* root1 = (const float*)d_in[9];
  const float* bias1 = (const float*)d_in[10];
  const float* bn1_g = (const float*)d_in[11];
  const float* bn1_b = (const float*)d_in[12];
  const float* e2_w1 = (const float*)d_in[13];
  const float* e2_b1 = (const float*)d_in[14];
  const float* e2_w2 = (const float*)d_in[15];
  const float* e2_b2 = (const float*)d_in[16];
  const float* root2 = (const float*)d_in[17];
  const float* bias2 = (const float*)d_in[18];
  const float* bn2_g = (const float*)d_in[19];
  const float* bn2_b = (const float*)d_in[20];
  const float* fc_w  = (const float*)d_in[21];
  const float* fc_b  = (const float*)d_in[22];
  float* out = (float*)d_out;

  float* ws = (float*)d_ws;
  const long NM = (long)NN*32;                 // 1,600,000
  float* bufA  = ws;                           // conv1 agg -> h1 (in place)
  float* bufB  = ws + NM;                      // conv2 agg -> h2 (in place)
  float* cnt   = ws + 2*NM;                    // in-degree
  float* stats = ws + 2*NM + NN;               // [0..63]=bn1, [64..127]=bn2
  float* psum  = stats + 128;                  // [G][32]
  float* pcnt  = psum + GG*32;                 // [G]
  unsigned short* Bt1 = (unsigned short*)(pcnt + GG);
  unsigned short* Bt2 = Bt1 + 32*288;

  // zero everything up to the Bt tables (they are fully rewritten by prep)
  size_t zero_bytes = (size_t)(2*NM + NN + 128 + GG*32 + GG) * 4;
  hipMemsetAsync(d_ws, 0, zero_bytes, stream);

  prep_bt_k<<<172, 256, 0, stream>>>(e1_w2, e1_b2, e2_w2, e2_b2, Bt1, Bt2);

  const int EBLK = (EE + 63) / 64;             // 7813
  conv_msg_k<6, 8, 3, 288, 9, 9, 1><<<EBLK, 256, 0, stream>>>(
      x, ei, ea, e1_w1, e1_b1, Bt1, bufA, cnt, EE);
  node_update_k<6><<<256, 256, 0, stream>>>(x, root1, bias1, cnt, bufA, stats, NN);
  bn_relu_k<<<(int)((NM + 255)/256), 256, 0, stream>>>(bufA, stats, bn1_g, bn1_b,
                                                       1.f/NN, (int)NM);
  conv_msg_k<32, 32, 5, 1088, 34, 17, 0><<<EBLK, 256, 0, stream>>>(
      bufA, ei, ea, e2_w1, e2_b1, Bt2, bufB, cnt, EE);
  node_update_k<32><<<256, 256, 0, stream>>>(bufA, root2, bias2, cnt, bufB, stats + 64, NN);
  bn_pool_k<<<(NN + 7)/8, 256, 0, stream>>>(bufB, stats + 64, bn2_g, bn2_b, batch,
                                            psum, pcnt, 1.f/NN, NN);
  final_k<<<2, 256, 0, stream>>>(psum, pcnt, gattr, fc_w, fc_b, out, GG);
}

// Round 3
// 453.105 us; speedup vs baseline: 1.1490x; 1.1490x over previous
//
#include <hip/hip_runtime.h>

#define NN 50000
#define EE 500000
#define GG 512

typedef _Float16 f16x8 __attribute__((ext_vector_type(8)));
typedef _Float16 f16x2 __attribute__((ext_vector_type(2)));
typedef float f32x16 __attribute__((ext_vector_type(16)));

union F16x8U { f16x8 v8; f16x2 v2[4]; unsigned u[4]; };

__device__ __forceinline__ unsigned splat_h(float a){
  return __builtin_bit_cast(unsigned, __builtin_amdgcn_cvt_pkrtz(a, a));
}

// ---------------------------------------------------------------------------
// Prep: f16 tables.
//  Bt1[o][ki] ki=8k+i  (KP=288): k<32 -> w2a[k*192+i*32+o], k==32 -> b2a, else 0
//  Bt2[o][ki] ki=32k+i (KP=1088): k<32 -> w2b[k*1024+i*32+o], k==32 -> b2b, else 0
//  xh[n][8] = f16(x[n][0..5]), pads 0
// ---------------------------------------------------------------------------
__launch_bounds__(256)
__global__ void prep_k(const float* __restrict__ x,
                       const float* __restrict__ w2a, const float* __restrict__ b2a,
                       const float* __restrict__ w2b, const float* __restrict__ b2b,
                       _Float16* __restrict__ xh, _Float16* __restrict__ Bt1,
                       _Float16* __restrict__ Bt2)
{
  int idx = blockIdx.x*256 + threadIdx.x;
  if (idx < 32*288){
    int o = idx / 288, ki = idx % 288;
    int k = ki >> 3, i = ki & 7;
    float v = 0.f;
    if (i < 6){
      if (k < 32)       v = w2a[k*192 + i*32 + o];
      else if (k == 32) v = b2a[i*32 + o];
    }
    Bt1[idx] = (_Float16)v;
  } else if (idx < 32*288 + 32*1088){
    int j = idx - 32*288;
    int o = j / 1088, ki = j % 1088;
    int k = ki >> 5, i = ki & 31;
    float v = 0.f;
    if (k < 32)       v = w2b[k*1024 + i*32 + o];
    else if (k == 32) v = b2b[i*32 + o];
    Bt2[j] = (_Float16)v;
  } else {
    int j = idx - (32*288 + 32*1088);
    if (j < NN*8){
      int n = j >> 3, i = j & 7;
      xh[j] = (_Float16)((i < 6) ? x[n*6 + i] : 0.f);
    }
  }
}

// ---------------------------------------------------------------------------
// NNConv messages: block = 128 edges (4 waves x 32 edges), mfma 32x32x16 f16.
// z[e][ki] = h'[e][k] * x'[e][i]; msg = z @ Bt; scatter atomicAdd to agg[dst].
// A row = lane&31 (edge), k-octet = 8*(lane>>5)+j.  B col = lane&31, same
// octets.  D: col = lane&31, row = (reg&3) + 8*(reg>>2) + 4*(lane>>5).
// ---------------------------------------------------------------------------
template<int CONV>
__launch_bounds__(256, 4)
__global__ void conv_msg_k(const _Float16* __restrict__ xh,
                           const int* __restrict__ ei,
                           const float* __restrict__ ea,
                           const float* __restrict__ w1,
                           const float* __restrict__ b1,
                           const _Float16* __restrict__ Btg,
                           float* __restrict__ agg, float* __restrict__ cnt)
{
  constexpr int KP = (CONV == 1) ? 288 : 1088;
  constexpr int NT = KP / 16;
  __shared__ unsigned hs2[128][37];       // splatted half2 of h', kk = 0..35

  const int tid = threadIdx.x;
  const int e0  = blockIdx.x * 128;

  // cooperative h' = relu(ea@w1 + b1), stored as splatted half2
  {
    int e  = tid >> 1;                    // 0..127
    int kb = (tid & 1) * 16;
    int eg = e0 + e;
    bool valid = eg < EE;
    float eav[5];
    #pragma unroll
    for (int q = 0; q < 5; ++q) eav[q] = valid ? ea[(long)eg*5 + q] : 0.f;
    #pragma unroll
    for (int k = kb; k < kb + 16; ++k){
      float a = b1[k];
      #pragma unroll
      for (int q = 0; q < 5; ++q) a += eav[q] * w1[q*32 + k];
      hs2[e][k] = splat_h(fmaxf(a, 0.f));
    }
    if (kb == 16){
      hs2[e][32] = splat_h(1.f);          // bias row (h' = 1)
      hs2[e][33] = 0u; hs2[e][34] = 0u; hs2[e][35] = 0u;
    }
  }
  __syncthreads();

  const int lane = tid & 63;
  const int wave = tid >> 6;
  const int col  = lane & 31;             // A-row (edge) AND B-col (output)
  const int hi   = lane >> 5;
  const int el   = wave*32 + col;         // block-local edge for A
  const int emy  = e0 + el;
  const int src  = (emy < EE) ? ei[emy] : 0;

  // x fragments (f16 pairs), register-resident
  F16x8U xa, xb;
  if (CONV == 1){
    xa.v8 = *(const f16x8*)(xh + (long)src*8);
    xb.v8 = xa.v8;
  } else {
    xa.v8 = *(const f16x8*)(xh + (long)src*32 + 8*hi);
    xb.v8 = *(const f16x8*)(xh + (long)src*32 + 16 + 8*hi);
  }

  // h' splats, register-resident (static indexing under full unroll)
  unsigned h2[(CONV == 1) ? 18 : 34];
  if (CONV == 1){
    #pragma unroll
    for (int t = 0; t < 18; ++t) h2[t] = hs2[el][2*t + hi];
  } else {
    #pragma unroll
    for (int kk = 0; kk < 34; ++kk) h2[kk] = hs2[el][kk];
  }

  f32x16 acc;
  #pragma unroll
  for (int r = 0; r < 16; ++r) acc[r] = 0.f;

  const _Float16* bp = Btg + (long)col*KP + 8*hi;
  #pragma unroll
  for (int t = 0; t < NT; ++t){
    f16x8 bf = *(const f16x8*)(bp + 16*t);
    f16x2 hv = __builtin_bit_cast(f16x2, h2[(CONV == 1) ? t : (t >> 1)]);
    const F16x8U& xs = (CONV == 1) ? xa : ((t & 1) ? xb : xa);
    F16x8U af;
    #pragma unroll
    for (int p = 0; p < 4; ++p) af.v2[p] = hv * xs.v2[p];
    acc = __builtin_amdgcn_mfma_f32_32x32x16_f16(af.v8, bf, acc, 0, 0, 0);
  }

  // scatter epilogue
  if (CONV == 1 && tid < 128){
    int eg = e0 + tid;
    if (eg < EE) atomicAdd(&cnt[ei[EE + eg]], 1.f);
  }
  #pragma unroll
  for (int g = 0; g < 4; ++g){
    #pragma unroll
    for (int r = 0; r < 4; ++r){
      int row = r + 8*g + 4*hi;
      int eg  = e0 + wave*32 + row;
      if (eg < EE){
        int d = ei[EE + eg];
        atomicAdd(&agg[(long)d*32 + col], acc[4*g + r]);
      }
    }
  }
}

// ---------------------------------------------------------------------------
// h = agg/max(cnt,1) + x@root + bias (in place), accumulate BN stats.
// ---------------------------------------------------------------------------
template<int IN_C>
__launch_bounds__(256)
__global__ void node_update_k(const float* __restrict__ xin, const float* __restrict__ root,
                              const float* __restrict__ bias, const float* __restrict__ cnt,
                              float* __restrict__ buf, float* __restrict__ stats, int N)
{
  __shared__ float rs[IN_C*32];
  __shared__ float bs[32];
  __shared__ float redS[4][32], redQ[4][32];
  int tid = threadIdx.x;
  for (int i = tid; i < IN_C*32; i += 256) rs[i] = root[i];
  if (tid < 32) bs[tid] = bias[tid];
  __syncthreads();
  int o = tid & 31, slot = tid >> 5;
  float s = 0.f, q = 0.f;
  for (int n = blockIdx.x*8 + slot; n < N; n += gridDim.x*8){
    float c = fmaxf(cnt[n], 1.f);
    float v = buf[(long)n*32 + o] / c + bs[o];
    const float* xrow = &xin[(long)n*IN_C];
    #pragma unroll
    for (int i = 0; i < IN_C; ++i) v += xrow[i] * rs[i*32 + o];
    buf[(long)n*32 + o] = v;
    s += v; q += v*v;
  }
  s += __shfl_xor(s, 32); q += __shfl_xor(q, 32);
  int wv = tid >> 6;
  if ((tid & 63) < 32){ redS[wv][o] = s; redQ[wv][o] = q; }
  __syncthreads();
  if (tid < 32){
    float ts = 0.f, tq = 0.f;
    #pragma unroll
    for (int w = 0; w < 4; ++w){ ts += redS[w][tid]; tq += redQ[w][tid]; }
    atomicAdd(&stats[tid], ts); atomicAdd(&stats[32 + tid], tq);
  }
}

__launch_bounds__(256)
__global__ void bn_relu_k(float* __restrict__ buf, _Float16* __restrict__ bufh,
                          const float* __restrict__ stats,
                          const float* __restrict__ gg, const float* __restrict__ bb,
                          float invN, int total)
{
  int i = blockIdx.x*256 + threadIdx.x;
  if (i < total){
    int o = i & 31;
    float mu  = stats[o] * invN;
    float var = stats[32+o] * invN - mu*mu;
    float v = fmaxf((buf[i] - mu) * rsqrtf(var + 1e-5f) * gg[o] + bb[o], 0.f);
    buf[i]  = v;
    bufh[i] = (_Float16)v;
  }
}

__launch_bounds__(256)
__global__ void bn_pool_k(const float* __restrict__ buf, const float* __restrict__ stats,
                          const float* __restrict__ gg, const float* __restrict__ bb,
                          const int* __restrict__ batch, float* __restrict__ psum,
                          float* __restrict__ pcnt, float invN, int N)
{
  int tid = threadIdx.x;
  int o = tid & 31;
  int n = blockIdx.x*8 + (tid >> 5);
  if (n < N){
    int gr = batch[n];
    float mu  = stats[o] * invN;
    float var = stats[32+o] * invN - mu*mu;
    float v = fmaxf((buf[(long)n*32+o] - mu) * rsqrtf(var + 1e-5f) * gg[o] + bb[o], 0.f);
    atomicAdd(&psum[gr*32 + o], v);
    if (o == 0) atomicAdd(&pcnt[gr], 1.f);
  }
}

__launch_bounds__(256)
__global__ void final_k(const float* __restrict__ psum, const float* __restrict__ pcnt,
                        const float* __restrict__ gattr, const float* __restrict__ fcw,
                        const float* __restrict__ fcb, float* __restrict__ out, int G)
{
  int g = blockIdx.x*256 + threadIdx.x;
  if (g < G){
    float c = fmaxf(pcnt[g], 1.f);
    float o0 = fcb[0], o1 = fcb[1], o2 = fcb[2];
    #pragma unroll
    for (int j = 0; j < 32; ++j){
      float p = psum[g*32+j] / c;
      o0 += p*fcw[j*3+0]; o1 += p*fcw[j*3+1]; o2 += p*fcw[j*3+2];
    }
    #pragma unroll
    for (int j = 0; j < 4; ++j){
      float a = gattr[g*4+j];
      o0 += a*fcw[(32+j)*3+0]; o1 += a*fcw[(32+j)*3+1]; o2 += a*fcw[(32+j)*3+2];
    }
    out[g*3+0] = o0; out[g*3+1] = o1; out[g*3+2] = o2;
  }
}

// ---------------------------------------------------------------------------
extern "C" void kernel_launch(void* const* d_in, const int* in_sizes, int n_in,
                              void* d_out, int out_size, void* d_ws, size_t ws_size,
                              hipStream_t stream)
{
  const float* x     = (const float*)d_in[0];
  const int*   ei    = (const int*)  d_in[1];
  const float* ea    = (const float*)d_in[2];
  const int*   batch = (const int*)  d_in[3];
  const float* gattr = (const float*)d_in[4];
  const float* e1_w1 = (const float*)d_in[5];
  const float* e1_b1 = (const float*)d_in[6];
  const float* e1_w2 = (const float*)d_in[7];
  const float* e1_b2 = (const float*)d_in[8];
  const float* root1 = (const float*)d_in[9];
  const float* bias1 = (const float*)d_in[10];
  const float* bn1_g = (const float*)d_in[11];
  const float* bn1_b = (const float*)d_in[12];
  const float* e2_w1 = (const float*)d_in[13];
  const float* e2_b1 = (const float*)d_in[14];
  const float* e2_w2 = (const float*)d_in[15];
  const float* e2_b2 = (const float*)d_in[16];
  const float* root2 = (const float*)d_in[17];
  const float* bias2 = (const float*)d_in[18];
  const float* bn2_g = (const float*)d_in[19];
  const float* bn2_b = (const float*)d_in[20];
  const float* fc_w  = (const float*)d_in[21];
  const float* fc_b  = (const float*)d_in[22];
  float* out = (float*)d_out;

  float* ws = (float*)d_ws;
  const long NM = (long)NN*32;
  float* bufA  = ws;                      // conv1 agg -> h1 (in place)
  float* bufB  = ws + NM;                 // conv2 agg -> h2 (in place)
  float* cnt   = ws + 2*NM;
  float* stats = ws + 2*NM + NN;          // 0..63 bn1, 64..127 bn2
  float* psum  = stats + 128;             // [G][32]
  float* pcnt  = psum + GG*32;
  _Float16* bufAh = (_Float16*)(pcnt + GG);   // [N][32] f16 of h1
  _Float16* xh    = bufAh + (long)NN*32;      // [N][8]  f16 of x (padded)
  _Float16* Bt1   = xh + (long)NN*8;          // [32][288]
  _Float16* Bt2   = Bt1 + 32*288;             // [32][1088]

  size_t zero_bytes = (size_t)(2*NM + NN + 128 + GG*32 + GG) * 4;
  (void)hipMemsetAsync(d_ws, 0, zero_bytes, stream);

  const int PREP_ELEMS = 32*288 + 32*1088 + NN*8;
  prep_k<<<(PREP_ELEMS + 255)/256, 256, 0, stream>>>(x, e1_w2, e1_b2, e2_w2, e2_b2,
                                                     xh, Bt1, Bt2);

  const int EBLK = (EE + 127) / 128;      // 3907
  conv_msg_k<1><<<EBLK, 256, 0, stream>>>(xh, ei, ea, e1_w1, e1_b1, Bt1, bufA, cnt);
  node_update_k<6><<<256, 256, 0, stream>>>(x, root1, bias1, cnt, bufA, stats, NN);
  bn_relu_k<<<(int)((NM + 255)/256), 256, 0, stream>>>(bufA, bufAh, stats, bn1_g, bn1_b,
                                                       1.f/NN, (int)NM);
  conv_msg_k<2><<<EBLK, 256, 0, stream>>>(bufAh, ei, ea, e2_w1, e2_b1, Bt2, bufB, cnt);
  node_update_k<32><<<256, 256, 0, stream>>>(bufA, root2, bias2, cnt, bufB, stats + 64, NN);
  bn_pool_k<<<(NN + 7)/8, 256, 0, stream>>>(bufB, stats + 64, bn2_g, bn2_b, batch,
                                            psum, pcnt, 1.f/NN, NN);
  final_k<<<2, 256, 0, stream>>>(psum, pcnt, gattr, fc_w, fc_b, out, GG);
}